// Round 1
// baseline (128.061 us; speedup 1.0000x reference)
//
#include <hip/hip_runtime.h>

// BatchIndependentLoss: SupCon-style loss, B=2048, V=2, D=256, N=4096.
// loss = -mean_i( l_pos_i - (W_i - e^{lp}*lp) / u_new[i%B] )
//   l_ij = (a_i.a_j - a_i.a_i)/T   (row max == self-dot analytically)
//   E_i  = sum_j exp(l_ij) (all j), W_i = sum_j exp(l_ij)*l_ij
//   neg excludes only j = i^2048 -> subtract pos term analytically
//   u_new[b] = 0.1*u[idx[b]] + 0.9*(E_b - exp(lp_b))

#define BSZ   2048
#define NROW  4096
#define DDIM  256
#define INVT  (1.0f / 0.07f)

typedef __attribute__((ext_vector_type(8))) __bf16 bf16x8;
typedef __attribute__((ext_vector_type(4))) float f32x4;

__device__ __forceinline__ short f2bs(float x) {
    __bf16 b = (__bf16)x;
    return __builtin_bit_cast(short, b);
}

// contrast row i = v*B + b  ->  features row b*V + v  (fp32, 256 elems)
__device__ __forceinline__ const float* crow_ptr(const float* feats, int i) {
    return feats + (((i & (BSZ - 1)) * 2 + (i >> 11)) << 8);
}

// ---------------- prep: bf16 convert (optional), self-dots, zero E/W -------
template <bool WRITE_CM>
__global__ __launch_bounds__(256) void prep_kernel(const float* __restrict__ feats,
        float* __restrict__ selfdot, float* __restrict__ EWzero,
        short* __restrict__ Cm) {
    int z = blockIdx.x * 256 + threadIdx.x;
    if (z < 2 * NROW) EWzero[z] = 0.0f;           // zero E and W (contiguous)

    int lane = threadIdx.x & 63;
    int row  = (blockIdx.x << 2) + (threadIdx.x >> 6);   // 1024 blocks * 4 waves
    const float4* src = (const float4*)crow_ptr(feats, row);
    float4 v = src[lane];
    float a0 = (float)(__bf16)v.x;
    float a1 = (float)(__bf16)v.y;
    float a2 = (float)(__bf16)v.z;
    float a3 = (float)(__bf16)v.w;
    if (WRITE_CM) {
        short4 h = make_short4(f2bs(v.x), f2bs(v.y), f2bs(v.z), f2bs(v.w));
        *(short4*)(Cm + row * DDIM + (lane << 2)) = h;
    }
    float s = a0 * a0 + a1 * a1 + a2 * a2 + a3 * a3;   // self-dot of bf16-rounded row
    #pragma unroll
    for (int off = 32; off; off >>= 1) s += __shfl_xor(s, off, 64);
    if (lane == 0) selfdot[row] = s;
}

// ---------------- GEMM + fused row stats ----------------------------------
// 128x128 tile per block (grid 32x32), 4 waves each 64x64 (4x4 frags of 16x16x32).
// K staged in 4 chunks of 64; LDS rows padded 64->72 shorts (144 B, 16B-aligned,
// +4 bank shift/row) so frag ds_read_b128 hits the 8-cycle minimum.
template <bool FROM_CM>
__device__ __forceinline__ void stage_chunk(short* lds, const float* feats,
        const short* Cm, int tileBase, int kc, int tid) {
    if (FROM_CM) {
        // 128 rows x 64 bf16 = 1024 16B-chunks; 4 iters x 256 threads
        #pragma unroll
        for (int it = 0; it < 4; ++it) {
            int c = (it << 8) + tid;
            int r = c >> 3, c8 = c & 7;
            int4 v = *(const int4*)(Cm + (tileBase + r) * DDIM + (kc << 6) + (c8 << 3));
            *(int4*)&lds[r * 72 + (c8 << 3)] = v;
        }
    } else {
        // 128 rows x 64 f32 = 2048 float4-chunks; 8 iters, convert on the fly
        #pragma unroll
        for (int it = 0; it < 8; ++it) {
            int c = (it << 8) + tid;
            int r = c >> 4, c4 = c & 15;
            const float4* src = (const float4*)(crow_ptr(feats, tileBase + r) + (kc << 6));
            float4 v = src[c4];
            short4 h = make_short4(f2bs(v.x), f2bs(v.y), f2bs(v.z), f2bs(v.w));
            *(short4*)&lds[r * 72 + (c4 << 2)] = h;
        }
    }
}

template <bool FROM_CM>
__global__ __launch_bounds__(256) void gemm_stats(const float* __restrict__ feats,
        const short* __restrict__ Cm, const float* __restrict__ selfdot,
        float* __restrict__ E, float* __restrict__ W, float* __restrict__ Lpos) {
    __shared__ short As[128 * 72];
    __shared__ short Bs[128 * 72];
    int tid = threadIdx.x;
    int rowBase = blockIdx.y * 128;
    int colBase = blockIdx.x * 128;

    int lane = tid & 63;
    int wave = tid >> 6;
    int quad = lane >> 4;
    int l15  = lane & 15;
    int wr = (wave >> 1) * 64;   // wave's row-half within the 128 tile
    int wc = (wave & 1) * 64;    // wave's col-half

    f32x4 acc[4][4];
    #pragma unroll
    for (int a = 0; a < 4; ++a)
        #pragma unroll
        for (int b = 0; b < 4; ++b) acc[a][b] = (f32x4){0.f, 0.f, 0.f, 0.f};

    for (int kc = 0; kc < 4; ++kc) {
        if (kc) __syncthreads();
        stage_chunk<FROM_CM>(As, feats, Cm, rowBase, kc, tid);
        stage_chunk<FROM_CM>(Bs, feats, Cm, colBase, kc, tid);
        __syncthreads();
        #pragma unroll
        for (int kk = 0; kk < 2; ++kk) {
            int ko = (kk << 5) + (quad << 3);   // k offset in shorts within chunk
            bf16x8 af[4], bfr[4];
            #pragma unroll
            for (int t = 0; t < 4; ++t)
                af[t] = *(const bf16x8*)&As[(wr + t * 16 + l15) * 72 + ko];
            #pragma unroll
            for (int t = 0; t < 4; ++t)
                bfr[t] = *(const bf16x8*)&Bs[(wc + t * 16 + l15) * 72 + ko];
            #pragma unroll
            for (int rt = 0; rt < 4; ++rt)
                #pragma unroll
                for (int ct = 0; ct < 4; ++ct)
                    acc[rt][ct] = __builtin_amdgcn_mfma_f32_16x16x32_bf16(
                        af[rt], bfr[ct], acc[rt][ct], 0, 0, 0);
        }
    }

    // epilogue: C/D layout col = lane&15, row = quad*4 + reg  [m89/m91]
    float sd[4][4];
    #pragma unroll
    for (int rt = 0; rt < 4; ++rt)
        #pragma unroll
        for (int r = 0; r < 4; ++r)
            sd[rt][r] = selfdot[rowBase + wr + rt * 16 + (quad << 2) + r];

    float Ep[4][4] = {}, Wp[4][4] = {};
    #pragma unroll
    for (int rt = 0; rt < 4; ++rt) {
        #pragma unroll
        for (int ct = 0; ct < 4; ++ct) {
            int gcol = colBase + wc + ct * 16 + l15;
            #pragma unroll
            for (int r = 0; r < 4; ++r) {
                int grow = rowBase + wr + rt * 16 + (quad << 2) + r;
                float l = (acc[rt][ct][r] - sd[rt][r]) * INVT;
                float e = __expf(l);
                Ep[rt][r] += e;
                Wp[rt][r] += e * l;
                if (gcol == (grow ^ BSZ)) Lpos[grow] = l;  // unique writer grid-wide
            }
        }
    }
    // reduce over the 16 lanes (l15) sharing each row, then 1 atomic per row/wave
    #pragma unroll
    for (int rt = 0; rt < 4; ++rt) {
        #pragma unroll
        for (int r = 0; r < 4; ++r) {
            float e = Ep[rt][r], w = Wp[rt][r];
            #pragma unroll
            for (int off = 1; off < 16; off <<= 1) {
                e += __shfl_xor(e, off, 64);
                w += __shfl_xor(w, off, 64);
            }
            if (l15 == 0) {
                int grow = rowBase + wr + rt * 16 + (quad << 2) + r;
                atomicAdd(&E[grow], e);
                atomicAdd(&W[grow], w);
            }
        }
    }
}

// ---------------- finalize: u_new + scalar reduction -----------------------
__global__ __launch_bounds__(1024) void finalize_kernel(const int* __restrict__ index,
        const float* __restrict__ u, const float* __restrict__ E,
        const float* __restrict__ W, const float* __restrict__ Lpos,
        float* __restrict__ out) {
    __shared__ float unew[BSZ];
    __shared__ float partial[16];
    int tid = threadIdx.x;
    for (int b = tid; b < BSZ; b += 1024) {
        float lp = Lpos[b];
        float eneg = E[b] - __expf(lp);                 // remove pos from full sum
        unew[b] = 0.1f * u[index[b]] + 0.9f * eneg;     // (1-GAMMA), GAMMA
    }
    __syncthreads();
    float local = 0.0f;
    for (int i = tid; i < NROW; i += 1024) {
        float lp  = Lpos[i];
        float elp = __expf(lp);
        float wn  = W[i] - elp * lp;                    // W without pos term
        local += lp - wn / unew[i & (BSZ - 1)];
    }
    #pragma unroll
    for (int off = 32; off; off >>= 1) local += __shfl_xor(local, off, 64);
    if ((tid & 63) == 0) partial[tid >> 6] = local;
    __syncthreads();
    if (tid == 0) {
        float s = 0.0f;
        #pragma unroll
        for (int w = 0; w < 16; ++w) s += partial[w];
        out[0] = -s / (float)NROW;
    }
}

extern "C" void kernel_launch(void* const* d_in, const int* in_sizes, int n_in,
                              void* d_out, int out_size, void* d_ws, size_t ws_size,
                              hipStream_t stream) {
    const int*   index = (const int*)d_in[0];
    const float* feats = (const float*)d_in[1];
    const float* u     = (const float*)d_in[2];
    float* out = (float*)d_out;

    // ws layout: [selfdot|E|W|Lpos] (4x4096 f32 = 64 KB), then bf16 Cm (2 MB)
    float* selfdot = (float*)d_ws;
    float* E    = selfdot + NROW;
    float* W    = E + NROW;
    float* Lpos = W + NROW;
    short* Cm   = (short*)((char*)d_ws + 65536);
    bool use_cm = ws_size >= (size_t)65536 + (size_t)NROW * DDIM * 2;

    if (use_cm) {
        prep_kernel<true><<<1024, 256, 0, stream>>>(feats, selfdot, E, Cm);
        gemm_stats<true><<<dim3(32, 32), 256, 0, stream>>>(feats, Cm, selfdot, E, W, Lpos);
    } else {
        prep_kernel<false><<<1024, 256, 0, stream>>>(feats, selfdot, E, Cm);
        gemm_stats<false><<<dim3(32, 32), 256, 0, stream>>>(feats, Cm, selfdot, E, W, Lpos);
    }
    finalize_kernel<<<1, 1024, 0, stream>>>(index, u, E, W, Lpos, out);
}